// Round 6
// baseline (1038.413 us; speedup 1.0000x reference)
//
#include <hip/hip_runtime.h>
#include <math.h>

// GAT layer, round 6: DIAGNOSTIC round. Amplified (repeated, idempotent)
// copies of the suspect kernels so they exceed the 160us fill threshold and
// surface in rocprof top-5 with their own counters. dur_us will regress this
// round by design.
// N=8192, IN=512, D=64, ALPHA=0.2
//
// ws layout (float-slot units):
//   s1    : [8192] f32                      8192
//   s2    : [8192] f32                      8192
//   hFrag : [256 jblk][4 dt][64 lane] bf16x8 -> 262144 float slots
//   mask  : [8192 row][256 chunk] u32    -> 2097152 u32 slots (8 MB)
//   numP  : [1024][64][64] f32             4194304
//   denP  : [1024][64] f32                   65536
//   maskB : scratch 8 MB (diagnostic pack_b output, unused by attn)

#define NN 8192
#define KIN 512
#define DD 64
#define ALPHA 0.2f

using floatx4 = __attribute__((ext_vector_type(4))) float;
using bf16x8  = __attribute__((ext_vector_type(8))) __bf16;

// ------- Kernel 1: fused  h-tile GEMM -> {s1, s2, hFrag}  (h stays on-chip) -------
__global__ __launch_bounds__(256) void k_fused(const float* __restrict__ X,
                                               const float* __restrict__ W,
                                               const float* __restrict__ a,
                                               float* __restrict__ s1,
                                               float* __restrict__ s2,
                                               __bf16* __restrict__ hFrag) {
    __shared__ __align__(16) float smem[3200];  // XT[32*36]+WL[32*64] / reused as hT[32*66]
    float* XT = smem;             // [k][row], stride 36
    float* WL = smem + 32 * 36;   // [k][d]
    float* hT = smem;             // [row][d], stride 66 (reused after final sync)
    const int t = threadIdx.x;
    const int i0 = blockIdx.x * 32;
    const int rb = t >> 5;   // rows rb*4..+3
    const int db = t & 31;   // dims db*2..+1
    float acc[4][2] = {};

    for (int k0 = 0; k0 < KIN; k0 += 32) {
        {
            const int row = t >> 3, kq = t & 7;
            const float4 x4 = *(const float4*)(X + (size_t)(i0 + row) * KIN + k0 + kq * 4);
            XT[(kq * 4 + 0) * 36 + row] = x4.x;
            XT[(kq * 4 + 1) * 36 + row] = x4.y;
            XT[(kq * 4 + 2) * 36 + row] = x4.z;
            XT[(kq * 4 + 3) * 36 + row] = x4.w;
#pragma unroll
            for (int p = 0; p < 2; ++p) {
                const int q = p * 256 + t;  // 0..511
                const int kk = q >> 4, dq = q & 15;
                *(float4*)(WL + kk * 64 + dq * 4) =
                    *(const float4*)(W + (size_t)(k0 + kk) * DD + dq * 4);
            }
        }
        __syncthreads();
#pragma unroll
        for (int k = 0; k < 32; ++k) {
            const float4 xa = *(const float4*)(XT + k * 36 + rb * 4);
            const float2 wb = *(const float2*)(WL + k * 64 + db * 2);
            const float xv[4] = {xa.x, xa.y, xa.z, xa.w};
#pragma unroll
            for (int i = 0; i < 4; ++i) {
                acc[i][0] += xv[i] * wb.x;
                acc[i][1] += xv[i] * wb.y;
            }
        }
        __syncthreads();
    }
#pragma unroll
    for (int i = 0; i < 4; ++i) {
        hT[(rb * 4 + i) * 66 + db * 2 + 0] = acc[i][0];
        hT[(rb * 4 + i) * 66 + db * 2 + 1] = acc[i][1];
    }
    __syncthreads();
    {
        const int r = t >> 3, sub = t & 7;
        float p1 = 0.f, p2 = 0.f;
#pragma unroll
        for (int u = 0; u < 8; ++u) {
            const int d = sub * 8 + u;
            const float v = hT[r * 66 + d];
            p1 += v * a[d];
            p2 += v * a[64 + d];
        }
#pragma unroll
        for (int off = 1; off < 8; off <<= 1) {
            p1 += __shfl_xor(p1, off, 64);
            p2 += __shfl_xor(p2, off, 64);
        }
        if (sub == 0) {
            s1[i0 + r] = p1;
            s2[i0 + r] = p2;
        }
    }
    {
        const int lane = t & 63, dt = t >> 6;
        const int n = lane & 15, q = lane >> 4;
        bf16x8 v;
#pragma unroll
        for (int jj = 0; jj < 8; ++jj)
            v[jj] = (__bf16)hT[(q * 8 + jj) * 66 + dt * 16 + n];
        *(bf16x8*)(hFrag + ((size_t)blockIdx.x * 256 + t) * 8) = v;
    }
}

// ------- Kernel 2a: Adj -> bitmask, dword loads (256 B/instr), x8 AMPLIFIED -------
__global__ __launch_bounds__(256) void k_pack_a(const int* __restrict__ Adj,
                                                unsigned int* __restrict__ mask) {
    const int lane = threadIdx.x & 63;
    const int wid = (blockIdx.x * 256 + threadIdx.x) >> 6;
    const int nw = (gridDim.x * 256) >> 6;
#pragma unroll 1
    for (int rep = 0; rep < 8; ++rep) {
#pragma unroll 1
        for (int it = wid; it < (NN * NN / 512); it += nw) {
            const size_t base = (size_t)it * 512;
            unsigned long long m[8];
#pragma unroll
            for (int p = 0; p < 8; ++p) {
                const int v = Adj[base + (size_t)p * 64 + lane];
                m[p] = __ballot(v != 0);
            }
            if (lane == 0) {
                unsigned long long* o = (unsigned long long*)mask + (size_t)it * 8;
#pragma unroll
                for (int p = 0; p < 8; ++p) o[p] = m[p];
            }
        }
    }
}

// ------- Kernel 2b: DIAGNOSTIC ONLY — int4 loads (1 KB/instr), x8 AMPLIFIED -------
// Output bit-order is garbage (or-reduced); written to scratch maskB, never read.
__global__ __launch_bounds__(256) void k_pack_b(const int* __restrict__ Adj,
                                                unsigned int* __restrict__ maskB) {
    const int lane = threadIdx.x & 63;
    const int wid = (blockIdx.x * 256 + threadIdx.x) >> 6;
    const int nw = (gridDim.x * 256) >> 6;
#pragma unroll 1
    for (int rep = 0; rep < 8; ++rep) {
#pragma unroll 1
        for (int it = wid; it < (NN * NN / 2048); it += nw) {
            const size_t base = (size_t)it * 2048;
            unsigned long long m[8];
#pragma unroll
            for (int p = 0; p < 8; ++p) {
                const int4 v = *(const int4*)(Adj + base + (size_t)p * 256 + lane * 4);
                m[p] = __ballot((v.x | v.y | v.z | v.w) != 0);
            }
            if (lane == 0) {
                unsigned long long* o = (unsigned long long*)maskB + (size_t)it * 8;
#pragma unroll
                for (int p = 0; p < 8; ++p) o[p] = m[p];
            }
        }
    }
}

// ------- Kernel 3: MFMA attention, x4 AMPLIFIED (acc re-zeroed per rep) -------
__global__ __launch_bounds__(256, 4) void k_attn5(const bf16x8* __restrict__ hFrag,
                                                  const unsigned int* __restrict__ mask,
                                                  const float* __restrict__ s1,
                                                  const float* __restrict__ s2,
                                                  float* __restrict__ numP,
                                                  float* __restrict__ denP) {
    const int t = threadIdx.x;
    const int wv = t >> 6;
    const int lane = t & 63;
    const int n = lane & 15, q = lane >> 4;
    const int it = blockIdx.x >> 3, jc = blockIdx.x & 7;
    const int i0 = it * 64;
    const int row = i0 + wv * 16 + n;
    const float s1v = s1[row];
    const unsigned int* mrow = mask + (size_t)row * 256 + jc * 32;
    const int jbase = jc * 1024;

    bf16x8 ones;
#pragma unroll
    for (int u = 0; u < 8; ++u) ones[u] = (__bf16)1.0f;

    floatx4 acc[5];

#pragma unroll 1
    for (int rep = 0; rep < 4; ++rep) {
#pragma unroll
        for (int c = 0; c < 5; ++c) acc[c] = (floatx4){0.f, 0.f, 0.f, 0.f};
#pragma unroll 1
        for (int o = 0; o < 4; ++o) {
            const uint4 mA = *(const uint4*)(mrow + o * 8);
            const uint4 mB = *(const uint4*)(mrow + o * 8 + 4);
            const unsigned int mr[8] = {mA.x, mA.y, mA.z, mA.w, mB.x, mB.y, mB.z, mB.w};
#pragma unroll
            for (int k8 = 0; k8 < 8; ++k8) {
                const int ks = o * 8 + k8;
                const int j0 = jbase + ks * 32 + q * 8;
                const float4 z0 = *(const float4*)(s2 + j0);
                const float4 z1 = *(const float4*)(s2 + j0 + 4);
                const unsigned int bits = (mr[k8] >> (q * 8)) & 0xffu;
                const float zz[8] = {z0.x, z0.y, z0.z, z0.w, z1.x, z1.y, z1.z, z1.w};
                bf16x8 af;
#pragma unroll
                for (int u = 0; u < 8; ++u) {
                    const float s = s1v + zz[u];
                    const float l = fmaxf(s, ALPHA * s);
                    const float e = (bits & (1u << u)) ? __expf(l) : 0.f;
                    af[u] = (__bf16)e;
                }
                const bf16x8* hf = hFrag + ((size_t)(jc * 32 + ks) * 4) * 64 + lane;
#pragma unroll
                for (int dt = 0; dt < 4; ++dt)
                    acc[dt] = __builtin_amdgcn_mfma_f32_16x16x32_bf16(af, hf[dt * 64], acc[dt], 0, 0, 0);
                acc[4] = __builtin_amdgcn_mfma_f32_16x16x32_bf16(af, ones, acc[4], 0, 0, 0);
            }
        }
    }

    const size_t base = (size_t)blockIdx.x * 4096;
#pragma unroll
    for (int dt = 0; dt < 4; ++dt)
#pragma unroll
        for (int r = 0; r < 4; ++r)
            numP[base + (size_t)(wv * 16 + q * 4 + r) * 64 + dt * 16 + n] = acc[dt][r];

    if (n == 0) {
#pragma unroll
        for (int r = 0; r < 4; ++r)
            denP[(size_t)blockIdx.x * 64 + wv * 16 + q * 4 + r] = acc[4][r];
    }
}

// ------- Kernel 4: reduce partials + normalize -------
__global__ __launch_bounds__(256) void k_final(const float* __restrict__ numP,
                                               const float* __restrict__ denP,
                                               float* __restrict__ out) {
    const int idx = blockIdx.x * 256 + threadIdx.x;  // 0..524287
    const int i = idx >> 6, d = idx & 63;
    const int it = i >> 6, r = i & 63;
    float num = 0.f, den = 0.f;
#pragma unroll
    for (int c = 0; c < 8; ++c) {
        const size_t bx = (size_t)(it * 8 + c);
        num += numP[bx * 4096 + (size_t)r * 64 + d];
        den += denP[bx * 64 + r];
    }
    out[idx] = num / den;
}

extern "C" void kernel_launch(void* const* d_in, const int* in_sizes, int n_in,
                              void* d_out, int out_size, void* d_ws, size_t ws_size,
                              hipStream_t stream) {
    const float* X = (const float*)d_in[0];
    const int* Adj = (const int*)d_in[1];
    const float* W = (const float*)d_in[2];
    const float* a = (const float*)d_in[3];
    float* out = (float*)d_out;

    float* ws = (float*)d_ws;
    float* s1 = ws;                                  // 8192
    float* s2 = s1 + 8192;                           // 8192
    __bf16* hFrag = (__bf16*)(s2 + 8192);            // 262144 float slots
    unsigned int* mask = (unsigned int*)(s2 + 8192 + 262144);  // 2097152 u32
    float* numP = (float*)(s2 + 8192 + 262144 + 2097152);      // 1024*4096
    float* denP = numP + 1024 * 4096;                          // 1024*64
    unsigned int* maskB = (unsigned int*)(denP + 1024 * 64);   // 2097152 u32 scratch

    k_fused<<<256, 256, 0, stream>>>(X, W, a, s1, s2, hFrag);
    k_pack_a<<<2048, 256, 0, stream>>>(Adj, mask);
    k_pack_b<<<2048, 256, 0, stream>>>(Adj, maskB);
    k_attn5<<<1024, 256, 0, stream>>>((const bf16x8*)hFrag, mask, s1, s2, numP, denP);
    k_final<<<2048, 256, 0, stream>>>(numP, denP, out);
}

// Round 7
// 442.956 us; speedup vs baseline: 2.3443x; 2.3443x over previous
//
#include <hip/hip_runtime.h>
#include <math.h>

// GAT layer, round 7: single fused MFMA attention kernel that streams Adj
// directly with wide nontemporal loads (no pack pre-pass, no mask buffer,
// no LDS). Theory: cold Adj ingest is outstanding-miss-latency-bound
// (~2 TB/s at 256B/instr); int4 (1KB/instr) x 2-step pipeline raises
// in-flight bytes ~8x.
// N=8192, IN=512, D=64, ALPHA=0.2
//
// ws layout (float-slot units):
//   s1    : [8192] f32                      8192
//   s2    : [8192] f32                      8192
//   hFrag : [256 jblk][4 dt][64 lane] bf16x8 -> 262144 float slots
//   numP  : [1024][64][64] f32             4194304
//   denP  : [1024][64] f32                   65536

#define NN 8192
#define KIN 512
#define DD 64
#define ALPHA 0.2f

using floatx4 = __attribute__((ext_vector_type(4))) float;
using bf16x8  = __attribute__((ext_vector_type(8))) __bf16;
using intx4   = __attribute__((ext_vector_type(4))) int;

// ------- Kernel 1: fused  h-tile GEMM -> {s1, s2, hFrag}  (h stays on-chip) -------
__global__ __launch_bounds__(256) void k_fused(const float* __restrict__ X,
                                               const float* __restrict__ W,
                                               const float* __restrict__ a,
                                               float* __restrict__ s1,
                                               float* __restrict__ s2,
                                               __bf16* __restrict__ hFrag) {
    __shared__ __align__(16) float smem[3200];  // XT[32*36]+WL[32*64] / reused as hT[32*66]
    float* XT = smem;             // [k][row], stride 36
    float* WL = smem + 32 * 36;   // [k][d]
    float* hT = smem;             // [row][d], stride 66 (reused after final sync)
    const int t = threadIdx.x;
    const int i0 = blockIdx.x * 32;
    const int rb = t >> 5;   // rows rb*4..+3
    const int db = t & 31;   // dims db*2..+1
    float acc[4][2] = {};

    for (int k0 = 0; k0 < KIN; k0 += 32) {
        {
            const int row = t >> 3, kq = t & 7;
            const float4 x4 = *(const float4*)(X + (size_t)(i0 + row) * KIN + k0 + kq * 4);
            XT[(kq * 4 + 0) * 36 + row] = x4.x;
            XT[(kq * 4 + 1) * 36 + row] = x4.y;
            XT[(kq * 4 + 2) * 36 + row] = x4.z;
            XT[(kq * 4 + 3) * 36 + row] = x4.w;
#pragma unroll
            for (int p = 0; p < 2; ++p) {
                const int q = p * 256 + t;  // 0..511
                const int kk = q >> 4, dq = q & 15;
                *(float4*)(WL + kk * 64 + dq * 4) =
                    *(const float4*)(W + (size_t)(k0 + kk) * DD + dq * 4);
            }
        }
        __syncthreads();
#pragma unroll
        for (int k = 0; k < 32; ++k) {
            const float4 xa = *(const float4*)(XT + k * 36 + rb * 4);
            const float2 wb = *(const float2*)(WL + k * 64 + db * 2);
            const float xv[4] = {xa.x, xa.y, xa.z, xa.w};
#pragma unroll
            for (int i = 0; i < 4; ++i) {
                acc[i][0] += xv[i] * wb.x;
                acc[i][1] += xv[i] * wb.y;
            }
        }
        __syncthreads();
    }
#pragma unroll
    for (int i = 0; i < 4; ++i) {
        hT[(rb * 4 + i) * 66 + db * 2 + 0] = acc[i][0];
        hT[(rb * 4 + i) * 66 + db * 2 + 1] = acc[i][1];
    }
    __syncthreads();
    {
        const int r = t >> 3, sub = t & 7;
        float p1 = 0.f, p2 = 0.f;
#pragma unroll
        for (int u = 0; u < 8; ++u) {
            const int d = sub * 8 + u;
            const float v = hT[r * 66 + d];
            p1 += v * a[d];
            p2 += v * a[64 + d];
        }
#pragma unroll
        for (int off = 1; off < 8; off <<= 1) {
            p1 += __shfl_xor(p1, off, 64);
            p2 += __shfl_xor(p2, off, 64);
        }
        if (sub == 0) {
            s1[i0 + r] = p1;
            s2[i0 + r] = p2;
        }
    }
    {
        const int lane = t & 63, dt = t >> 6;
        const int n = lane & 15, q = lane >> 4;
        bf16x8 v;
#pragma unroll
        for (int jj = 0; jj < 8; ++jj)
            v[jj] = (__bf16)hT[(q * 8 + jj) * 66 + dt * 16 + n];
        *(bf16x8*)(hFrag + ((size_t)blockIdx.x * 256 + t) * 8) = v;
    }
}

// ------- Kernel 2: fused Adj-stream + masked-softmax numerator via MFMA -------
// grid = 128 i-tiles x 8 j-chunks = 1024 blocks, 256 threads (4 waves), NO LDS.
// Lane (n = lane&15, q = lane>>4) of wave wv owns E-row i0+wv*16+n; per K-step
// (32 j) it reads its 8 Adj ints as two nontemporal int4 (1KB/wave-instr) and
// builds the A-fragment in registers. 2-step pipeline keeps ~4KB/wave in flight.
__global__ __launch_bounds__(256, 4) void k_attn6(const bf16x8* __restrict__ hFrag,
                                                  const int* __restrict__ Adj,
                                                  const float* __restrict__ s1,
                                                  const float* __restrict__ s2,
                                                  float* __restrict__ numP,
                                                  float* __restrict__ denP) {
    const int t = threadIdx.x;
    const int wv = t >> 6;
    const int lane = t & 63;
    const int n = lane & 15, q = lane >> 4;
    const int it = blockIdx.x >> 3, jc = blockIdx.x & 7;
    const int i0 = it * 64;
    const int row = i0 + wv * 16 + n;
    const float s1v = s1[row];
    const int jbase = jc * 1024;
    // this lane's Adj base: its row, its q-octet within the chunk
    const int* adjL = Adj + (size_t)row * NN + jbase + q * 8;
    const float* s2L = s2 + jbase + q * 8;
    const bf16x8* hfL = hFrag + (size_t)(jc * 32) * 4 * 64 + lane;

    bf16x8 ones;
#pragma unroll
    for (int u = 0; u < 8; ++u) ones[u] = (__bf16)1.0f;

    floatx4 acc[5] = {};  // 4 d-tiles + denominator (B = ones)

#pragma unroll 1
    for (int ks = 0; ks < 32; ks += 2) {
        // ---- issue both steps' Adj loads up front (4 KB/wave in flight) ----
        const intx4 a00 = __builtin_nontemporal_load((const intx4*)(adjL + ks * 32));
        const intx4 a01 = __builtin_nontemporal_load((const intx4*)(adjL + ks * 32 + 4));
        const intx4 a10 = __builtin_nontemporal_load((const intx4*)(adjL + ks * 32 + 32));
        const intx4 a11 = __builtin_nontemporal_load((const intx4*)(adjL + ks * 32 + 36));
        const float4 z00 = *(const float4*)(s2L + ks * 32);
        const float4 z01 = *(const float4*)(s2L + ks * 32 + 4);
        const float4 z10 = *(const float4*)(s2L + ks * 32 + 32);
        const float4 z11 = *(const float4*)(s2L + ks * 32 + 36);
#pragma unroll
        for (int sub = 0; sub < 2; ++sub) {
            const intx4 aa = sub ? a10 : a00;
            const intx4 ab = sub ? a11 : a01;
            const float4 za = sub ? z10 : z00;
            const float4 zb = sub ? z11 : z01;
            const int am[8] = {aa.x, aa.y, aa.z, aa.w, ab.x, ab.y, ab.z, ab.w};
            const float zz[8] = {za.x, za.y, za.z, za.w, zb.x, zb.y, zb.z, zb.w};
            bf16x8 af;
#pragma unroll
            for (int u = 0; u < 8; ++u) {
                const float s = s1v + zz[u];
                const float l = fmaxf(s, ALPHA * s);  // leaky-relu (alpha<1)
                const float e = am[u] ? __expf(l) : 0.f;
                af[u] = (__bf16)e;
            }
            const bf16x8* hf = hfL + (size_t)(ks + sub) * 4 * 64;
#pragma unroll
            for (int dt = 0; dt < 4; ++dt)
                acc[dt] = __builtin_amdgcn_mfma_f32_16x16x32_bf16(af, hf[dt * 64], acc[dt], 0, 0, 0);
            acc[4] = __builtin_amdgcn_mfma_f32_16x16x32_bf16(af, ones, acc[4], 0, 0, 0);
        }
    }

    // numerator partials: D row m = q*4+reg, col = dt*16+n
    const size_t base = (size_t)blockIdx.x * 4096;
#pragma unroll
    for (int dt = 0; dt < 4; ++dt)
#pragma unroll
        for (int r = 0; r < 4; ++r)
            numP[base + (size_t)(wv * 16 + q * 4 + r) * 64 + dt * 16 + n] = acc[dt][r];

    // denominator: every col of acc[4] holds the row-sum; lane n==0 writes its 4 rows
    if (n == 0) {
#pragma unroll
        for (int r = 0; r < 4; ++r)
            denP[(size_t)blockIdx.x * 64 + wv * 16 + q * 4 + r] = acc[4][r];
    }
}

// ------- Kernel 3: reduce partials + normalize -------
__global__ __launch_bounds__(256) void k_final(const float* __restrict__ numP,
                                               const float* __restrict__ denP,
                                               float* __restrict__ out) {
    const int idx = blockIdx.x * 256 + threadIdx.x;  // 0..524287
    const int i = idx >> 6, d = idx & 63;
    const int it = i >> 6, r = i & 63;
    float num = 0.f, den = 0.f;
#pragma unroll
    for (int c = 0; c < 8; ++c) {
        const size_t bx = (size_t)(it * 8 + c);
        num += numP[bx * 4096 + (size_t)r * 64 + d];
        den += denP[bx * 64 + r];
    }
    out[idx] = num / den;
}

extern "C" void kernel_launch(void* const* d_in, const int* in_sizes, int n_in,
                              void* d_out, int out_size, void* d_ws, size_t ws_size,
                              hipStream_t stream) {
    const float* X = (const float*)d_in[0];
    const int* Adj = (const int*)d_in[1];
    const float* W = (const float*)d_in[2];
    const float* a = (const float*)d_in[3];
    float* out = (float*)d_out;

    float* ws = (float*)d_ws;
    float* s1 = ws;                                  // 8192
    float* s2 = s1 + 8192;                           // 8192
    __bf16* hFrag = (__bf16*)(s2 + 8192);            // 262144 float slots
    float* numP = (float*)(s2 + 8192 + 262144);      // 1024*4096
    float* denP = numP + 1024 * 4096;                // 1024*64

    k_fused<<<256, 256, 0, stream>>>(X, W, a, s1, s2, hFrag);
    k_attn6<<<1024, 256, 0, stream>>>((const bf16x8*)hFrag, Adj, s1, s2, numP, denP);
    k_final<<<2048, 256, 0, stream>>>(numP, denP, out);
}

// Round 8
// 410.889 us; speedup vs baseline: 2.5272x; 1.0780x over previous
//
#include <hip/hip_runtime.h>
#include <math.h>

// GAT layer, round 8: attention restructured around global_load_lds (LDS-DMA)
// deep-pipelined Adj streaming. 512 blocks x 16 rows x full-j sweep; Adj double
// buffered in LDS (2 x 33KB); waves split K-steps 4-way with per-wave partials.
// Theory under test: cold-HBM read is per-CU miss-concurrency capped (~2.1TB/s)
// for VGPR loads; LDS-DMA path may have a deeper queue.
// N=8192, IN=512, D=64, ALPHA=0.2
//
// ws layout (float-slot units):
//   s1    : [8192] f32                      8192
//   s2    : [8192] f32                      8192
//   hFrag : [256 jblk][4 dt][64 lane] bf16x8 -> 262144 float slots
//   numP  : [512 blk][4 wv][16 r][64 d] f32  2097152
//   denP  : [512 blk][4 wv][16 r] f32          32768

#define NN 8192
#define KIN 512
#define DD 64
#define ALPHA 0.2f

#define WJ 512           // j-window per stage
#define NWIN (NN / WJ)   // 16 windows
#define ASTR 516         // LDS row stride in ints (16B-aligned rows, bank-uniform b128)
#define ABUF (16 * ASTR) // ints per buffer

using floatx4 = __attribute__((ext_vector_type(4))) float;
using bf16x8  = __attribute__((ext_vector_type(8))) __bf16;

__device__ __forceinline__ void glds16(const int* g, int* l) {
    __builtin_amdgcn_global_load_lds((const __attribute__((address_space(1))) void*)g,
                                     (__attribute__((address_space(3))) void*)l, 16, 0, 0);
}

// ------- Kernel 1: fused  h-tile GEMM -> {s1, s2, hFrag}  (h stays on-chip) -------
__global__ __launch_bounds__(256) void k_fused(const float* __restrict__ X,
                                               const float* __restrict__ W,
                                               const float* __restrict__ a,
                                               float* __restrict__ s1,
                                               float* __restrict__ s2,
                                               __bf16* __restrict__ hFrag) {
    __shared__ __align__(16) float smem[3200];  // XT[32*36]+WL[32*64] / reused as hT[32*66]
    float* XT = smem;             // [k][row], stride 36
    float* WL = smem + 32 * 36;   // [k][d]
    float* hT = smem;             // [row][d], stride 66 (reused after final sync)
    const int t = threadIdx.x;
    const int i0 = blockIdx.x * 32;
    const int rb = t >> 5;   // rows rb*4..+3
    const int db = t & 31;   // dims db*2..+1
    float acc[4][2] = {};

    for (int k0 = 0; k0 < KIN; k0 += 32) {
        {
            const int row = t >> 3, kq = t & 7;
            const float4 x4 = *(const float4*)(X + (size_t)(i0 + row) * KIN + k0 + kq * 4);
            XT[(kq * 4 + 0) * 36 + row] = x4.x;
            XT[(kq * 4 + 1) * 36 + row] = x4.y;
            XT[(kq * 4 + 2) * 36 + row] = x4.z;
            XT[(kq * 4 + 3) * 36 + row] = x4.w;
#pragma unroll
            for (int p = 0; p < 2; ++p) {
                const int q = p * 256 + t;  // 0..511
                const int kk = q >> 4, dq = q & 15;
                *(float4*)(WL + kk * 64 + dq * 4) =
                    *(const float4*)(W + (size_t)(k0 + kk) * DD + dq * 4);
            }
        }
        __syncthreads();
#pragma unroll
        for (int k = 0; k < 32; ++k) {
            const float4 xa = *(const float4*)(XT + k * 36 + rb * 4);
            const float2 wb = *(const float2*)(WL + k * 64 + db * 2);
            const float xv[4] = {xa.x, xa.y, xa.z, xa.w};
#pragma unroll
            for (int i = 0; i < 4; ++i) {
                acc[i][0] += xv[i] * wb.x;
                acc[i][1] += xv[i] * wb.y;
            }
        }
        __syncthreads();
    }
#pragma unroll
    for (int i = 0; i < 4; ++i) {
        hT[(rb * 4 + i) * 66 + db * 2 + 0] = acc[i][0];
        hT[(rb * 4 + i) * 66 + db * 2 + 1] = acc[i][1];
    }
    __syncthreads();
    {
        const int r = t >> 3, sub = t & 7;
        float p1 = 0.f, p2 = 0.f;
#pragma unroll
        for (int u = 0; u < 8; ++u) {
            const int d = sub * 8 + u;
            const float v = hT[r * 66 + d];
            p1 += v * a[d];
            p2 += v * a[64 + d];
        }
#pragma unroll
        for (int off = 1; off < 8; off <<= 1) {
            p1 += __shfl_xor(p1, off, 64);
            p2 += __shfl_xor(p2, off, 64);
        }
        if (sub == 0) {
            s1[i0 + r] = p1;
            s2[i0 + r] = p2;
        }
    }
    {
        const int lane = t & 63, dt = t >> 6;
        const int n = lane & 15, q = lane >> 4;
        bf16x8 v;
#pragma unroll
        for (int jj = 0; jj < 8; ++jj)
            v[jj] = (__bf16)hT[(q * 8 + jj) * 66 + dt * 16 + n];
        *(bf16x8*)(hFrag + ((size_t)blockIdx.x * 256 + t) * 8) = v;
    }
}

// ------- Kernel 2: Adj-stream (global_load_lds dbuf) + masked softmax MFMA -------
// 512 blocks x 256 threads (4 waves); block = rows i0..i0+15, all 8192 j.
// Wave wv stages rows wv*4..+3 of each window (8 x 1KB glds instrs) and computes
// K-steps wv*4..+3 (per-wave j-partials, reduced in k_final).
__global__ __launch_bounds__(256) void k_attn7(const bf16x8* __restrict__ hFrag,
                                               const int* __restrict__ Adj,
                                               const float* __restrict__ s1,
                                               const float* __restrict__ s2,
                                               float* __restrict__ numP,
                                               float* __restrict__ denP) {
    __shared__ int lds_adj[2 * ABUF];  // 2 x 33KB
    const int t = threadIdx.x;
    const int wv = t >> 6, lane = t & 63;
    const int n = lane & 15, q = lane >> 4;
    const int i0 = blockIdx.x * 16;
    const float s1v = s1[i0 + n];

    bf16x8 ones;
#pragma unroll
    for (int u = 0; u < 8; ++u) ones[u] = (__bf16)1.0f;

    floatx4 acc[5] = {};  // 4 d-tiles + denominator (B = ones); per-wave j-partials

    // ---- stage issuer: window w -> buffer buf (8 x 1KB glds per wave) ----
    auto issue = [&](int w, int buf) {
        const int jg0 = w * WJ;
#pragma unroll
        for (int r4 = 0; r4 < 4; ++r4) {
            const int r = wv * 4 + r4;
            const int* gsrc = Adj + (size_t)(i0 + r) * NN + jg0 + lane * 4;
            int* ldst = lds_adj + buf * ABUF + r * ASTR;  // wave-uniform base
            glds16(gsrc, ldst);
            glds16(gsrc + 256, ldst + 256);
        }
    };

    issue(0, 0);
    issue(1, 1);

#pragma unroll 1
    for (int w = 0; w < NWIN; ++w) {
        const int buf = w & 1;
        __syncthreads();  // vmcnt drain: this window's (and prefetched) loads landed
        // ---- compute: wave wv handles K-steps wv*4..+3 of this window ----
        const int* ldsb = lds_adj + buf * ABUF + n * ASTR;
#pragma unroll
        for (int k4 = 0; k4 < 4; ++k4) {
            const int ks = wv * 4 + k4;
            const int jg = w * WJ + ks * 32 + q * 8;
            const float4 z0 = *(const float4*)(s2 + jg);
            const float4 z1 = *(const float4*)(s2 + jg + 4);
            const int4 m0 = *(const int4*)(ldsb + ks * 32 + q * 8);
            const int4 m1 = *(const int4*)(ldsb + ks * 32 + q * 8 + 4);
            const int am[8] = {m0.x, m0.y, m0.z, m0.w, m1.x, m1.y, m1.z, m1.w};
            const float zz[8] = {z0.x, z0.y, z0.z, z0.w, z1.x, z1.y, z1.z, z1.w};
            bf16x8 af;
#pragma unroll
            for (int u = 0; u < 8; ++u) {
                const float s = s1v + zz[u];
                const float l = fmaxf(s, ALPHA * s);  // leaky-relu (alpha<1)
                const float e = am[u] ? __expf(l) : 0.f;
                af[u] = (__bf16)e;
            }
            const bf16x8* hf = hFrag + (size_t)(w * 16 + ks) * 4 * 64 + lane;
#pragma unroll
            for (int dt = 0; dt < 4; ++dt)
                acc[dt] = __builtin_amdgcn_mfma_f32_16x16x32_bf16(af, hf[dt * 64], acc[dt], 0, 0, 0);
            acc[4] = __builtin_amdgcn_mfma_f32_16x16x32_bf16(af, ones, acc[4], 0, 0, 0);
        }
        __syncthreads();  // all waves done reading buf before it is overwritten
        if (w + 2 < NWIN) issue(w + 2, buf);
    }

    // ---- per-wave partial writes: D row m = q*4+reg, col d = dt*16+n ----
    const size_t base = ((size_t)blockIdx.x * 4 + wv) * 1024;
#pragma unroll
    for (int dt = 0; dt < 4; ++dt)
#pragma unroll
        for (int r = 0; r < 4; ++r)
            numP[base + (size_t)(q * 4 + r) * 64 + dt * 16 + n] = acc[dt][r];

    if (n == 0) {
#pragma unroll
        for (int r = 0; r < 4; ++r)
            denP[((size_t)blockIdx.x * 4 + wv) * 16 + q * 4 + r] = acc[4][r];
    }
}

// ------- Kernel 3: reduce 4 wave-partials + normalize -------
__global__ __launch_bounds__(256) void k_final(const float* __restrict__ numP,
                                               const float* __restrict__ denP,
                                               float* __restrict__ out) {
    const int idx = blockIdx.x * 256 + threadIdx.x;  // 0..524287
    const int i = idx >> 6, d = idx & 63;
    const int blk = i >> 4, r = i & 15;
    float num = 0.f, den = 0.f;
#pragma unroll
    for (int wv = 0; wv < 4; ++wv) {
        num += numP[((size_t)blk * 4 + wv) * 1024 + (size_t)r * 64 + d];
        den += denP[((size_t)blk * 4 + wv) * 16 + r];
    }
    out[idx] = num / den;
}

extern "C" void kernel_launch(void* const* d_in, const int* in_sizes, int n_in,
                              void* d_out, int out_size, void* d_ws, size_t ws_size,
                              hipStream_t stream) {
    const float* X = (const float*)d_in[0];
    const int* Adj = (const int*)d_in[1];
    const float* W = (const float*)d_in[2];
    const float* a = (const float*)d_in[3];
    float* out = (float*)d_out;

    float* ws = (float*)d_ws;
    float* s1 = ws;                                  // 8192
    float* s2 = s1 + 8192;                           // 8192
    __bf16* hFrag = (__bf16*)(s2 + 8192);            // 262144 float slots
    float* numP = (float*)(s2 + 8192 + 262144);      // 512*4*1024
    float* denP = numP + 512 * 4 * 1024;             // 512*4*16

    k_fused<<<256, 256, 0, stream>>>(X, W, a, s1, s2, hFrag);
    k_attn7<<<512, 256, 0, stream>>>((const bf16x8*)hFrag, Adj, s1, s2, numP, denP);
    k_final<<<2048, 256, 0, stream>>>(numP, denP, out);
}

// Round 9
// 396.784 us; speedup vs baseline: 2.6171x; 1.0355x over previous
//
#include <hip/hip_runtime.h>
#include <math.h>

// GAT layer, round 9: R8 structure with 4 blocks/CU (half-j blocks, half-size
// LDS windows) to raise the cold-miss issue duty cycle via cross-block overlap
// of the per-window vmcnt drains.
// N=8192, IN=512, D=64, ALPHA=0.2
//
// ws layout (float-slot units):
//   s1    : [8192] f32                        8192
//   s2    : [8192] f32                        8192
//   hFrag : [256 jblk][4 dt][64 lane] bf16x8 -> 262144 float slots
//   numP  : [1024 blk][4 wv][16 r][64 d] f32  4194304
//   denP  : [1024 blk][4 wv][16 r] f32          65536

#define NN 8192
#define KIN 512
#define DD 64
#define ALPHA 0.2f

#define WJ 256           // j-window per stage (ints)
#define JSPAN 4096       // j-range per block
#define NWIN (JSPAN/WJ)  // 16 windows
#define ASTR 260         // LDS row stride in ints (16B-aligned rows)
#define ABUF (16 * ASTR) // ints per buffer (16.6 KB)

using floatx4 = __attribute__((ext_vector_type(4))) float;
using bf16x8  = __attribute__((ext_vector_type(8))) __bf16;

__device__ __forceinline__ void glds16(const int* g, int* l) {
    __builtin_amdgcn_global_load_lds((const __attribute__((address_space(1))) void*)g,
                                     (__attribute__((address_space(3))) void*)l, 16, 0, 0);
}

// ------- Kernel 1: fused  h-tile GEMM -> {s1, s2, hFrag}  (h stays on-chip) -------
__global__ __launch_bounds__(256) void k_fused(const float* __restrict__ X,
                                               const float* __restrict__ W,
                                               const float* __restrict__ a,
                                               float* __restrict__ s1,
                                               float* __restrict__ s2,
                                               __bf16* __restrict__ hFrag) {
    __shared__ __align__(16) float smem[3200];  // XT[32*36]+WL[32*64] / reused as hT[32*66]
    float* XT = smem;             // [k][row], stride 36
    float* WL = smem + 32 * 36;   // [k][d]
    float* hT = smem;             // [row][d], stride 66 (reused after final sync)
    const int t = threadIdx.x;
    const int i0 = blockIdx.x * 32;
    const int rb = t >> 5;   // rows rb*4..+3
    const int db = t & 31;   // dims db*2..+1
    float acc[4][2] = {};

    for (int k0 = 0; k0 < KIN; k0 += 32) {
        {
            const int row = t >> 3, kq = t & 7;
            const float4 x4 = *(const float4*)(X + (size_t)(i0 + row) * KIN + k0 + kq * 4);
            XT[(kq * 4 + 0) * 36 + row] = x4.x;
            XT[(kq * 4 + 1) * 36 + row] = x4.y;
            XT[(kq * 4 + 2) * 36 + row] = x4.z;
            XT[(kq * 4 + 3) * 36 + row] = x4.w;
#pragma unroll
            for (int p = 0; p < 2; ++p) {
                const int q = p * 256 + t;  // 0..511
                const int kk = q >> 4, dq = q & 15;
                *(float4*)(WL + kk * 64 + dq * 4) =
                    *(const float4*)(W + (size_t)(k0 + kk) * DD + dq * 4);
            }
        }
        __syncthreads();
#pragma unroll
        for (int k = 0; k < 32; ++k) {
            const float4 xa = *(const float4*)(XT + k * 36 + rb * 4);
            const float2 wb = *(const float2*)(WL + k * 64 + db * 2);
            const float xv[4] = {xa.x, xa.y, xa.z, xa.w};
#pragma unroll
            for (int i = 0; i < 4; ++i) {
                acc[i][0] += xv[i] * wb.x;
                acc[i][1] += xv[i] * wb.y;
            }
        }
        __syncthreads();
    }
#pragma unroll
    for (int i = 0; i < 4; ++i) {
        hT[(rb * 4 + i) * 66 + db * 2 + 0] = acc[i][0];
        hT[(rb * 4 + i) * 66 + db * 2 + 1] = acc[i][1];
    }
    __syncthreads();
    {
        const int r = t >> 3, sub = t & 7;
        float p1 = 0.f, p2 = 0.f;
#pragma unroll
        for (int u = 0; u < 8; ++u) {
            const int d = sub * 8 + u;
            const float v = hT[r * 66 + d];
            p1 += v * a[d];
            p2 += v * a[64 + d];
        }
#pragma unroll
        for (int off = 1; off < 8; off <<= 1) {
            p1 += __shfl_xor(p1, off, 64);
            p2 += __shfl_xor(p2, off, 64);
        }
        if (sub == 0) {
            s1[i0 + r] = p1;
            s2[i0 + r] = p2;
        }
    }
    {
        const int lane = t & 63, dt = t >> 6;
        const int n = lane & 15, q = lane >> 4;
        bf16x8 v;
#pragma unroll
        for (int jj = 0; jj < 8; ++jj)
            v[jj] = (__bf16)hT[(q * 8 + jj) * 66 + dt * 16 + n];
        *(bf16x8*)(hFrag + ((size_t)blockIdx.x * 256 + t) * 8) = v;
    }
}

// ------- Kernel 2: Adj-stream (glds dbuf, 4 blocks/CU) + masked softmax MFMA -------
// 1024 blocks x 256 threads (4 waves); block = 16 rows x 4096 j (j-half).
// Wave wv stages rows wv*4..+3 of each 256-j window (4 x 1KB glds) and computes
// K-steps wv*2..+1 (per-wave j-partials, reduced in k_final).
__global__ __launch_bounds__(256) void k_attn8(const bf16x8* __restrict__ hFrag,
                                               const int* __restrict__ Adj,
                                               const float* __restrict__ s1,
                                               const float* __restrict__ s2,
                                               float* __restrict__ numP,
                                               float* __restrict__ denP) {
    __shared__ int lds_adj[2 * ABUF];  // 2 x 16.6 KB -> 4 blocks/CU
    const int t = threadIdx.x;
    const int wv = t >> 6, lane = t & 63;
    const int n = lane & 15, q = lane >> 4;
    const int i0 = (blockIdx.x >> 1) * 16;
    const int jb0 = (blockIdx.x & 1) * JSPAN;
    const float s1v = s1[i0 + n];

    bf16x8 ones;
#pragma unroll
    for (int u = 0; u < 8; ++u) ones[u] = (__bf16)1.0f;

    floatx4 acc[5] = {};  // 4 d-tiles + denominator (B = ones); per-wave j-partials

    // ---- stage issuer: window w -> buffer buf (4 x 1KB glds per wave) ----
    auto issue = [&](int w, int buf) {
        const int jg0 = jb0 + w * WJ;
#pragma unroll
        for (int r4 = 0; r4 < 4; ++r4) {
            const int r = wv * 4 + r4;
            const int* gsrc = Adj + (size_t)(i0 + r) * NN + jg0 + lane * 4;
            int* ldst = lds_adj + buf * ABUF + r * ASTR;  // wave-uniform base
            glds16(gsrc, ldst);
        }
    };

    issue(0, 0);
    issue(1, 1);

#pragma unroll 1
    for (int w = 0; w < NWIN; ++w) {
        const int buf = w & 1;
        __syncthreads();  // drain: this window's (and prefetched) loads landed
        // ---- compute: wave wv handles K-steps wv*2..+1 of this window ----
        const int* ldsb = lds_adj + buf * ABUF + n * ASTR;
#pragma unroll
        for (int k2 = 0; k2 < 2; ++k2) {
            const int ks = wv * 2 + k2;           // 0..7 within window
            const int jg = jb0 + w * WJ + ks * 32 + q * 8;
            const float4 z0 = *(const float4*)(s2 + jg);
            const float4 z1 = *(const float4*)(s2 + jg + 4);
            const int4 m0 = *(const int4*)(ldsb + ks * 32 + q * 8);
            const int4 m1 = *(const int4*)(ldsb + ks * 32 + q * 8 + 4);
            const int am[8] = {m0.x, m0.y, m0.z, m0.w, m1.x, m1.y, m1.z, m1.w};
            const float zz[8] = {z0.x, z0.y, z0.z, z0.w, z1.x, z1.y, z1.z, z1.w};
            bf16x8 af;
#pragma unroll
            for (int u = 0; u < 8; ++u) {
                const float s = s1v + zz[u];
                const float l = fmaxf(s, ALPHA * s);  // leaky-relu (alpha<1)
                const float e = am[u] ? __expf(l) : 0.f;
                af[u] = (__bf16)e;
            }
            const bf16x8* hf = hFrag + (size_t)(jg >> 5) * 4 * 64 + lane;
#pragma unroll
            for (int dt = 0; dt < 4; ++dt)
                acc[dt] = __builtin_amdgcn_mfma_f32_16x16x32_bf16(af, hf[dt * 64], acc[dt], 0, 0, 0);
            acc[4] = __builtin_amdgcn_mfma_f32_16x16x32_bf16(af, ones, acc[4], 0, 0, 0);
        }
        __syncthreads();  // all waves done reading buf before it is overwritten
        if (w + 2 < NWIN) issue(w + 2, buf);
    }

    // ---- per-wave partial writes: D row m = q*4+reg, col d = dt*16+n ----
    const size_t base = ((size_t)blockIdx.x * 4 + wv) * 1024;
#pragma unroll
    for (int dt = 0; dt < 4; ++dt)
#pragma unroll
        for (int r = 0; r < 4; ++r)
            numP[base + (size_t)(q * 4 + r) * 64 + dt * 16 + n] = acc[dt][r];

    if (n == 0) {
#pragma unroll
        for (int r = 0; r < 4; ++r)
            denP[((size_t)blockIdx.x * 4 + wv) * 16 + q * 4 + r] = acc[4][r];
    }
}

// ------- Kernel 3: reduce 8 partials (2 j-halves x 4 waves) + normalize -------
__global__ __launch_bounds__(256) void k_final(const float* __restrict__ numP,
                                               const float* __restrict__ denP,
                                               float* __restrict__ out) {
    const int idx = blockIdx.x * 256 + threadIdx.x;  // 0..524287
    const int i = idx >> 6, d = idx & 63;
    const int itile = i >> 4, r = i & 15;
    float num = 0.f, den = 0.f;
#pragma unroll
    for (int jh = 0; jh < 2; ++jh) {
        const int b = itile * 2 + jh;
#pragma unroll
        for (int wv = 0; wv < 4; ++wv) {
            num += numP[((size_t)b * 4 + wv) * 1024 + (size_t)r * 64 + d];
            den += denP[((size_t)b * 4 + wv) * 16 + r];
        }
    }
    out[idx] = num / den;
}

extern "C" void kernel_launch(void* const* d_in, const int* in_sizes, int n_in,
                              void* d_out, int out_size, void* d_ws, size_t ws_size,
                              hipStream_t stream) {
    const float* X = (const float*)d_in[0];
    const int* Adj = (const int*)d_in[1];
    const float* W = (const float*)d_in[2];
    const float* a = (const float*)d_in[3];
    float* out = (float*)d_out;

    float* ws = (float*)d_ws;
    float* s1 = ws;                                  // 8192
    float* s2 = s1 + 8192;                           // 8192
    __bf16* hFrag = (__bf16*)(s2 + 8192);            // 262144 float slots
    float* numP = (float*)(s2 + 8192 + 262144);      // 1024*4*1024
    float* denP = numP + 1024 * 4 * 1024;            // 1024*4*16

    k_fused<<<256, 256, 0, stream>>>(X, W, a, s1, s2, hFrag);
    k_attn8<<<1024, 256, 0, stream>>>((const bf16x8*)hFrag, Adj, s1, s2, numP, denP);
    k_final<<<2048, 256, 0, stream>>>(numP, denP, out);
}